// Round 2
// baseline (1134.812 us; speedup 1.0000x reference)
//
#include <hip/hip_runtime.h>
#include <hip/hip_bf16.h>

// ---------------------------------------------------------------------------
// 2-relation GNN layer, fp32 in/out (per reference dtypes).
//   h_tar = elu(feats0@W0+b0)  -> written straight to out plane 4
//   h_mask = elu(mask@W0+b0)   -> staged in out plane 1
//   g1 = elu(feats1@W1+b1)@A0 ; g2 = elu(feats2@W2+b2)@A1   ((S/c)@A == (S@A)/c)
//   sum_r[src] += g_r[dst]; cnt_r[src]++  over E edges (fp32 atomics)
//   planes 0..3 = elu(t+a1), elu(m+a1), elu(t+a2), elu(m+a2)
// Compute path: fp32 -> bf16 (round-half-up) -> mfma_f32_16x16x32_bf16.
// ---------------------------------------------------------------------------

typedef short  bf16x8 __attribute__((ext_vector_type(8)));
typedef float  f32x4  __attribute__((ext_vector_type(4)));

#define MFMA_BF16(a, b, c) __builtin_amdgcn_mfma_f32_16x16x32_bf16((a), (b), (c), 0, 0, 0)

__device__ __forceinline__ ushort f2bf(float f) {
  return (ushort)((__float_as_uint(f) + 0x8000u) >> 16);  // round-half-up, finite inputs
}
__device__ __forceinline__ float eluf(float x) {
  return x > 0.f ? x : (__expf(x) - 1.f);
}
// pack 8 consecutive fp32 -> bf16x8 (two aligned f32x4 loads)
__device__ __forceinline__ bf16x8 cvt8(const float* __restrict__ p) {
  f32x4 lo = *(const f32x4*)p;
  f32x4 hi = *(const f32x4*)(p + 4);
  union { unsigned u[4]; bf16x8 v; } r;
#pragma unroll
  for (int j = 0; j < 2; ++j) {
    unsigned a = __float_as_uint(lo[2 * j])     + 0x8000u;
    unsigned b = __float_as_uint(lo[2 * j + 1]) + 0x8000u;
    r.u[j] = (a >> 16) | (b & 0xFFFF0000u);
    unsigned c = __float_as_uint(hi[2 * j])     + 0x8000u;
    unsigned d = __float_as_uint(hi[2 * j + 1]) + 0x8000u;
    r.u[2 + j] = (c >> 16) | (d & 0xFFFF0000u);
  }
  return r.v;
}

// ---------------------------------------------------------------------------
// Pack fp32 W0/W1/W2 (128x64) and A0/A1 (64x64) into bf16 MFMA B-fragment
// order. Frag (kc,ct), lane l (q=l>>4, c=l&15): elem i = W[(kc*32+q*8+i)*64 + ct*16+c]
// Layout: W0 @0 (16 frags*512), W1 @8192, W2 @16384, A0 @24576 (8), A1 @28672 (8)
// ---------------------------------------------------------------------------
__global__ __launch_bounds__(256) void pack_frags_kernel(
    const float* __restrict__ W0, const float* __restrict__ W1,
    const float* __restrict__ W2, const float* __restrict__ A0,
    const float* __restrict__ A1, ushort* __restrict__ out) {
  int gw   = (blockIdx.x * blockDim.x + threadIdx.x) >> 6;
  int lane = threadIdx.x & 63;
  if (gw >= 64) return;
  const float* src; ushort* dst; int f;
  if (gw < 16)      { src = W0; dst = out;         f = gw;      }
  else if (gw < 32) { src = W1; dst = out + 8192;  f = gw - 16; }
  else if (gw < 48) { src = W2; dst = out + 16384; f = gw - 32; }
  else if (gw < 56) { src = A0; dst = out + 24576; f = gw - 48; }
  else              { src = A1; dst = out + 28672; f = gw - 56; }
  int kc = f >> 2, ct = f & 3;
  int q = lane >> 4, c = lane & 15;
  ushort* d = dst + ((size_t)f * 64 + lane) * 8;
#pragma unroll
  for (int i = 0; i < 8; ++i)
    d[i] = f2bf(src[(kc * 32 + q * 8 + i) * 64 + ct * 16 + c]);
}

// ---------------------------------------------------------------------------
// Y = elu(X@W + b) [optionally @A] ; X: [M x 128] fp32, Y: [M x 64] fp32.
// One wave per 16-row tile. A-frag: m=lane&15, k=(lane>>4)*8+i (m89/m120);
// C/D: col=lane&15, row=(lane>>4)*4+reg (m89). Second GEMM (@A, K=64)
// round-trips the elu'd bf16 tile through wave-private LDS (stride 72 keeps
// 16B alignment; 2-way bank aliasing is free per m136).
// ---------------------------------------------------------------------------
template <bool HASA>
__global__ __launch_bounds__(256) void lin_elu_kernel(
    const float* __restrict__ X, const ushort* __restrict__ Wp,
    const float* __restrict__ bias, const ushort* __restrict__ Ap,
    float* __restrict__ Y, int Mtiles) {
  __shared__ ushort plds[4][16 * 72];
  int lane  = threadIdx.x & 63;
  int q     = lane >> 4, c = lane & 15;
  int wslot = threadIdx.x >> 6;
  int wid   = blockIdx.x * 4 + wslot;
  int nw    = gridDim.x * 4;

  bf16x8 bw[4][4];
#pragma unroll
  for (int kc = 0; kc < 4; ++kc)
#pragma unroll
    for (int ct = 0; ct < 4; ++ct)
      bw[kc][ct] = *(const bf16x8*)(Wp + (((kc << 2) | ct) * 64 + lane) * 8);

  float bv[4];
#pragma unroll
  for (int ct = 0; ct < 4; ++ct) bv[ct] = bias[ct * 16 + c];

  bf16x8 ba[2][4];
  if (HASA) {
#pragma unroll
    for (int kc = 0; kc < 2; ++kc)
#pragma unroll
      for (int ct = 0; ct < 4; ++ct)
        ba[kc][ct] = *(const bf16x8*)(Ap + (((kc << 2) | ct) * 64 + lane) * 8);
  }

  ushort* myp = plds[wslot];

  for (int t = wid; t < Mtiles; t += nw) {
    const float* xr = X + ((size_t)(t * 16 + c)) * 128 + q * 8;
    bf16x8 a0 = cvt8(xr);
    bf16x8 a1 = cvt8(xr + 32);
    bf16x8 a2 = cvt8(xr + 64);
    bf16x8 a3 = cvt8(xr + 96);

    f32x4 acc[4];
#pragma unroll
    for (int ct = 0; ct < 4; ++ct) {
      f32x4 a = {0.f, 0.f, 0.f, 0.f};
      a = MFMA_BF16(a0, bw[0][ct], a);
      a = MFMA_BF16(a1, bw[1][ct], a);
      a = MFMA_BF16(a2, bw[2][ct], a);
      a = MFMA_BF16(a3, bw[3][ct], a);
      acc[ct] = a;
    }

    float* yr = Y + ((size_t)t * 16) * 64;
    if (!HASA) {
#pragma unroll
      for (int ct = 0; ct < 4; ++ct)
#pragma unroll
        for (int r = 0; r < 4; ++r)
          yr[(q * 4 + r) * 64 + ct * 16 + c] = eluf(acc[ct][r] + bv[ct]);
    } else {
      // stage elu'd tile as bf16 in wave-private LDS, reload as A-fragments
#pragma unroll
      for (int ct = 0; ct < 4; ++ct)
#pragma unroll
        for (int r = 0; r < 4; ++r)
          myp[(q * 4 + r) * 72 + ct * 16 + c] = f2bf(eluf(acc[ct][r] + bv[ct]));
      bf16x8 p0 = *(const bf16x8*)(myp + c * 72 + q * 8);
      bf16x8 p1 = *(const bf16x8*)(myp + c * 72 + 32 + q * 8);
      f32x4 acc2[4];
#pragma unroll
      for (int ct = 0; ct < 4; ++ct) {
        f32x4 a = {0.f, 0.f, 0.f, 0.f};
        a = MFMA_BF16(p0, ba[0][ct], a);
        a = MFMA_BF16(p1, ba[1][ct], a);
        acc2[ct] = a;
      }
#pragma unroll
      for (int ct = 0; ct < 4; ++ct)
#pragma unroll
        for (int r = 0; r < 4; ++r)
          yr[(q * 4 + r) * 64 + ct * 16 + c] = acc2[ct][r];
    }
  }
}

// ---------------------------------------------------------------------------
// Edge scatter: one wave per edge, lane j accumulates column j.
// unsafeAtomicAdd -> global_atomic_add_f32 (plain atomicAdd may CAS-loop).
// ---------------------------------------------------------------------------
__global__ __launch_bounds__(256) void scatter_kernel(
    const int* __restrict__ src1, const int* __restrict__ dst1,
    const float* __restrict__ g1, float* __restrict__ sum1, float* __restrict__ cnt1, int E1,
    const int* __restrict__ src2, const int* __restrict__ dst2,
    const float* __restrict__ g2, float* __restrict__ sum2, float* __restrict__ cnt2, int E2) {
  int lane = threadIdx.x & 63;
  int wid  = blockIdx.x * 4 + (threadIdx.x >> 6);
  int nw   = gridDim.x * 4;
  int tot  = E1 + E2;
  for (int e = wid; e < tot; e += nw) {
    const int *src, *dst; const float* g; float *sum, *cnt; int idx;
    if (e < E1) { src = src1; dst = dst1; g = g1; sum = sum1; cnt = cnt1; idx = e; }
    else        { src = src2; dst = dst2; g = g2; sum = sum2; cnt = cnt2; idx = e - E1; }
    int s = src[idx], d = dst[idx];
    float v = g[(size_t)d * 64 + lane];
    unsafeAtomicAdd(&sum[(size_t)s * 64 + lane], v);
    if (lane == 0) unsafeAtomicAdd(&cnt[s], 1.0f);
  }
}

// ---------------------------------------------------------------------------
// Finalize: one thread per float4. Reads t from out plane 4, m from out
// plane 1 (staged there), writes planes 0..3. In-thread read-before-write.
// ---------------------------------------------------------------------------
__global__ __launch_bounds__(256) void finalize_kernel(
    const float* __restrict__ sum1, const float* __restrict__ cnt1,
    const float* __restrict__ sum2, const float* __restrict__ cnt2,
    float* __restrict__ out, int N) {
  int i = blockIdx.x * blockDim.x + threadIdx.x;
  if (i >= N * 16) return;
  int n = i >> 4;
  size_t base  = ((size_t)i) << 2;
  size_t plane = (size_t)N * 64;
  f32x4 t = *(const f32x4*)(out + 4 * plane + base);
  f32x4 m = *(const f32x4*)(out + plane + base);
  float c1 = cnt1[n]; c1 = c1 > 0.f ? c1 : 1.f; float i1 = 1.f / c1;
  float c2 = cnt2[n]; c2 = c2 > 0.f ? c2 : 1.f; float i2 = 1.f / c2;
  f32x4 s1 = *(const f32x4*)(sum1 + base);
  f32x4 s2 = *(const f32x4*)(sum2 + base);
  f32x4 v1, m1, v2, m2;
#pragma unroll
  for (int j = 0; j < 4; ++j) {
    float a1 = s1[j] * i1, a2 = s2[j] * i2;
    v1[j] = eluf(t[j] + a1);
    m1[j] = eluf(m[j] + a1);
    v2[j] = eluf(t[j] + a2);
    m2[j] = eluf(m[j] + a2);
  }
  *(f32x4*)(out + base)             = v1;
  *(f32x4*)(out + plane + base)     = m1;
  *(f32x4*)(out + 2 * plane + base) = v2;
  *(f32x4*)(out + 3 * plane + base) = m2;
}

static inline int imin(int a, int b) { return a < b ? a : b; }

extern "C" void kernel_launch(void* const* d_in, const int* in_sizes, int n_in,
                              void* d_out, int out_size, void* d_ws, size_t ws_size,
                              hipStream_t stream) {
  const float* feats0 = (const float*)d_in[0];
  const float* feats1 = (const float*)d_in[1];
  const float* feats2 = (const float*)d_in[2];
  const float* maskf  = (const float*)d_in[3];
  const int* src1 = (const int*)d_in[4];
  const int* dst1 = (const int*)d_in[5];
  const int* src2 = (const int*)d_in[6];
  const int* dst2 = (const int*)d_in[7];
  const float* W0 = (const float*)d_in[8];
  const float* b0 = (const float*)d_in[9];
  const float* W1 = (const float*)d_in[10];
  const float* b1 = (const float*)d_in[11];
  const float* W2 = (const float*)d_in[12];
  const float* b2 = (const float*)d_in[13];
  const float* A0 = (const float*)d_in[14];
  const float* A1 = (const float*)d_in[15];

  int N  = in_sizes[0] / 128;
  int N1 = in_sizes[1] / 128;
  int N2 = in_sizes[2] / 128;
  int E  = in_sizes[4];

  float* out = (float*)d_out;
  size_t plane = (size_t)N * 64;
  float* h_tar  = out + 4 * plane;  // final value of plane 4 IS h_tar
  float* h_mask = out + plane;      // staged; finalize overwrites with mask1

  // Workspace (~75 MB): g1, g2, sum1, sum2, cnt1, cnt2, frags
  float* g1   = (float*)d_ws;                  // N1*64
  float* g2   = g1 + (size_t)N1 * 64;          // N2*64
  float* sum1 = g2 + (size_t)N2 * 64;          // N*64
  float* sum2 = sum1 + (size_t)N * 64;         // N*64
  float* cnt1 = sum2 + (size_t)N * 64;         // N
  float* cnt2 = cnt1 + N;                      // N
  ushort* frags = (ushort*)(cnt2 + N);         // 32768 ushorts (64 KB)

  // zero sums + counts (contiguous ~52 MB); ws is re-poisoned every launch
  hipMemsetAsync(sum1, 0, ((size_t)N * 128 + 2 * (size_t)N) * sizeof(float), stream);

  pack_frags_kernel<<<16, 256, 0, stream>>>(W0, W1, W2, A0, A1, frags);

  int t0 = N / 16, t1 = N1 / 16, t2 = N2 / 16;
  lin_elu_kernel<false><<<imin(768, (t0 + 3) / 4), 256, 0, stream>>>(
      feats0, frags, b0, nullptr, h_tar, t0);
  lin_elu_kernel<false><<<imin(768, (t0 + 3) / 4), 256, 0, stream>>>(
      maskf, frags, b0, nullptr, h_mask, t0);
  lin_elu_kernel<true><<<imin(768, (t1 + 3) / 4), 256, 0, stream>>>(
      feats1, frags + 8192, b1, frags + 24576, g1, t1);
  lin_elu_kernel<true><<<imin(768, (t2 + 3) / 4), 256, 0, stream>>>(
      feats2, frags + 16384, b2, frags + 28672, g2, t2);

  int totw = 2 * E;
  scatter_kernel<<<imin(4096, (totw + 3) / 4), 256, 0, stream>>>(
      src1, dst1, g1, sum1, cnt1, E, src2, dst2, g2, sum2, cnt2, E);

  finalize_kernel<<<(N * 16 + 255) / 256, 256, 0, stream>>>(
      sum1, cnt1, sum2, cnt2, out, N);
}

// Round 3
// 799.550 us; speedup vs baseline: 1.4193x; 1.4193x over previous
//
#include <hip/hip_runtime.h>
#include <hip/hip_bf16.h>

// ---------------------------------------------------------------------------
// 2-relation GNN layer, fp32 in/out.
//   h_tar = elu(feats0@W0+b0)  -> written straight to out plane 4
//   h_mask = elu(mask@W0+b0)   -> staged in out plane 1
//   g1 = elu(feats1@W1+b1)@A0 ; g2 = elu(feats2@W2+b2)@A1   ((S/c)@A == (S@A)/c)
//   CSR build (count/scan/bucket) over 2E edges, then gather-mean per node:
//   avg_r[v] = mean_{e: src_r[e]=v} g_r[dst_r[e]]
//   planes 0..3 = elu(t+avg1), elu(m+avg1), elu(t+avg2), elu(m+avg2)
// R2 post-mortem: 206M fp32 atomics ran at 251 G/s (atomic-op throughput
// wall, 820us). CSR costs 6.4M int atomics + register accumulation instead.
// ---------------------------------------------------------------------------

typedef short  bf16x8 __attribute__((ext_vector_type(8)));
typedef float  f32x4  __attribute__((ext_vector_type(4)));

#define MFMA_BF16(a, b, c) __builtin_amdgcn_mfma_f32_16x16x32_bf16((a), (b), (c), 0, 0, 0)

__device__ __forceinline__ ushort f2bf(float f) {
  return (ushort)((__float_as_uint(f) + 0x8000u) >> 16);  // round-half-up, finite inputs
}
__device__ __forceinline__ float eluf(float x) {
  return x > 0.f ? x : (__expf(x) - 1.f);
}
// pack 8 consecutive fp32 -> bf16x8 (two aligned f32x4 loads)
__device__ __forceinline__ bf16x8 cvt8(const float* __restrict__ p) {
  f32x4 lo = *(const f32x4*)p;
  f32x4 hi = *(const f32x4*)(p + 4);
  union { unsigned u[4]; bf16x8 v; } r;
#pragma unroll
  for (int j = 0; j < 2; ++j) {
    unsigned a = __float_as_uint(lo[2 * j])     + 0x8000u;
    unsigned b = __float_as_uint(lo[2 * j + 1]) + 0x8000u;
    r.u[j] = (a >> 16) | (b & 0xFFFF0000u);
    unsigned c = __float_as_uint(hi[2 * j])     + 0x8000u;
    unsigned d = __float_as_uint(hi[2 * j + 1]) + 0x8000u;
    r.u[2 + j] = (c >> 16) | (d & 0xFFFF0000u);
  }
  return r.v;
}

// ---------------------------------------------------------------------------
// Pack fp32 W0/W1/W2 (128x64) and A0/A1 (64x64) into bf16 MFMA B-fragment
// order. Frag (kc,ct), lane l (q=l>>4, c=l&15): elem i = W[(kc*32+q*8+i)*64+ct*16+c]
// Layout: W0 @0 (16 frags*512), W1 @8192, W2 @16384, A0 @24576 (8), A1 @28672 (8)
// ---------------------------------------------------------------------------
__global__ __launch_bounds__(256) void pack_frags_kernel(
    const float* __restrict__ W0, const float* __restrict__ W1,
    const float* __restrict__ W2, const float* __restrict__ A0,
    const float* __restrict__ A1, ushort* __restrict__ out) {
  int gw   = (blockIdx.x * blockDim.x + threadIdx.x) >> 6;
  int lane = threadIdx.x & 63;
  if (gw >= 64) return;
  const float* src; ushort* dst; int f;
  if (gw < 16)      { src = W0; dst = out;         f = gw;      }
  else if (gw < 32) { src = W1; dst = out + 8192;  f = gw - 16; }
  else if (gw < 48) { src = W2; dst = out + 16384; f = gw - 32; }
  else if (gw < 56) { src = A0; dst = out + 24576; f = gw - 48; }
  else              { src = A1; dst = out + 28672; f = gw - 56; }
  int kc = f >> 2, ct = f & 3;
  int q = lane >> 4, c = lane & 15;
  ushort* d = dst + ((size_t)f * 64 + lane) * 8;
#pragma unroll
  for (int i = 0; i < 8; ++i)
    d[i] = f2bf(src[(kc * 32 + q * 8 + i) * 64 + ct * 16 + c]);
}

// ---------------------------------------------------------------------------
// Y = elu(X@W + b) [optionally @A] ; X: [M x 128] fp32, Y: [M x 64] fp32.
// One wave per 16-row tile. A-frag: m=lane&15, k=(lane>>4)*8+i (m89/m120);
// C/D: col=lane&15, row=(lane>>4)*4+reg (m89).
// ---------------------------------------------------------------------------
template <bool HASA>
__global__ __launch_bounds__(256) void lin_elu_kernel(
    const float* __restrict__ X, const ushort* __restrict__ Wp,
    const float* __restrict__ bias, const ushort* __restrict__ Ap,
    float* __restrict__ Y, int Mtiles) {
  __shared__ ushort plds[4][16 * 72];
  int lane  = threadIdx.x & 63;
  int q     = lane >> 4, c = lane & 15;
  int wslot = threadIdx.x >> 6;
  int wid   = blockIdx.x * 4 + wslot;
  int nw    = gridDim.x * 4;

  bf16x8 bw[4][4];
#pragma unroll
  for (int kc = 0; kc < 4; ++kc)
#pragma unroll
    for (int ct = 0; ct < 4; ++ct)
      bw[kc][ct] = *(const bf16x8*)(Wp + (((kc << 2) | ct) * 64 + lane) * 8);

  float bv[4];
#pragma unroll
  for (int ct = 0; ct < 4; ++ct) bv[ct] = bias[ct * 16 + c];

  bf16x8 ba[2][4];
  if (HASA) {
#pragma unroll
    for (int kc = 0; kc < 2; ++kc)
#pragma unroll
      for (int ct = 0; ct < 4; ++ct)
        ba[kc][ct] = *(const bf16x8*)(Ap + (((kc << 2) | ct) * 64 + lane) * 8);
  }

  ushort* myp = plds[wslot];

  for (int t = wid; t < Mtiles; t += nw) {
    const float* xr = X + ((size_t)(t * 16 + c)) * 128 + q * 8;
    bf16x8 a0 = cvt8(xr);
    bf16x8 a1 = cvt8(xr + 32);
    bf16x8 a2 = cvt8(xr + 64);
    bf16x8 a3 = cvt8(xr + 96);

    f32x4 acc[4];
#pragma unroll
    for (int ct = 0; ct < 4; ++ct) {
      f32x4 a = {0.f, 0.f, 0.f, 0.f};
      a = MFMA_BF16(a0, bw[0][ct], a);
      a = MFMA_BF16(a1, bw[1][ct], a);
      a = MFMA_BF16(a2, bw[2][ct], a);
      a = MFMA_BF16(a3, bw[3][ct], a);
      acc[ct] = a;
    }

    float* yr = Y + ((size_t)t * 16) * 64;
    if (!HASA) {
#pragma unroll
      for (int ct = 0; ct < 4; ++ct)
#pragma unroll
        for (int r = 0; r < 4; ++r)
          yr[(q * 4 + r) * 64 + ct * 16 + c] = eluf(acc[ct][r] + bv[ct]);
    } else {
      // stage elu'd tile as bf16 in wave-private LDS, reload as A-fragments
#pragma unroll
      for (int ct = 0; ct < 4; ++ct)
#pragma unroll
        for (int r = 0; r < 4; ++r)
          myp[(q * 4 + r) * 72 + ct * 16 + c] = f2bf(eluf(acc[ct][r] + bv[ct]));
      bf16x8 p0 = *(const bf16x8*)(myp + c * 72 + q * 8);
      bf16x8 p1 = *(const bf16x8*)(myp + c * 72 + 32 + q * 8);
      f32x4 acc2[4];
#pragma unroll
      for (int ct = 0; ct < 4; ++ct) {
        f32x4 a = {0.f, 0.f, 0.f, 0.f};
        a = MFMA_BF16(p0, ba[0][ct], a);
        a = MFMA_BF16(p1, ba[1][ct], a);
        acc2[ct] = a;
      }
#pragma unroll
      for (int ct = 0; ct < 4; ++ct)
#pragma unroll
        for (int r = 0; r < 4; ++r)
          yr[(q * 4 + r) * 64 + ct * 16 + c] = acc2[ct][r];
    }
  }
}

// ---------------------------------------------------------------------------
// CSR build. Key space: [0, 2N): relation1 nodes 0..N-1, relation2 N..2N-1.
// ---------------------------------------------------------------------------
__global__ __launch_bounds__(256) void count_kernel(
    const int* __restrict__ src1, const int* __restrict__ src2,
    int* __restrict__ cnt, int E, int N) {
  int e = blockIdx.x * blockDim.x + threadIdx.x;
  if (e < E)           atomicAdd(&cnt[src1[e]], 1);
  else if (e < 2 * E)  atomicAdd(&cnt[N + src2[e - E]], 1);
}

// scan stage 1: per-block (2048 elems) sums
__global__ __launch_bounds__(256) void scan_sums_kernel(
    const int* __restrict__ cnt, int* __restrict__ partial, int n) {
  __shared__ int lds[256];
  int t = threadIdx.x, base = blockIdx.x * 2048 + t * 8;
  int s = 0;
#pragma unroll
  for (int j = 0; j < 8; ++j) { int i = base + j; s += (i < n) ? cnt[i] : 0; }
  lds[t] = s; __syncthreads();
  for (int off = 128; off > 0; off >>= 1) {
    if (t < off) lds[t] += lds[t + off];
    __syncthreads();
  }
  if (t == 0) partial[blockIdx.x] = lds[0];
}

// scan stage 2: single-block exclusive scan of partials (nb <= 256);
// thread nb-1 also writes row_ptr[n] = grand total.
__global__ __launch_bounds__(256) void scan_partials_kernel(
    int* __restrict__ partial, int* __restrict__ row_ptr, int nb, int n) {
  __shared__ int lds[256];
  int t = threadIdx.x;
  int v = (t < nb) ? partial[t] : 0;
  lds[t] = v; __syncthreads();
  for (int off = 1; off < 256; off <<= 1) {
    int x = lds[t];
    int a = (t >= off) ? lds[t - off] : 0;
    __syncthreads();
    lds[t] = x + a;
    __syncthreads();
  }
  int incl = lds[t];
  if (t < nb) partial[t] = incl - v;          // exclusive
  if (t == nb - 1) row_ptr[n] = incl;          // total = 2E
}

// scan stage 3: recompute local sums, block-exclusive-scan thread sums,
// write row_ptr and cursor (bucket cursors start at row begin).
__global__ __launch_bounds__(256) void scan_write_kernel(
    const int* __restrict__ cnt, const int* __restrict__ partial,
    int* __restrict__ row_ptr, int* __restrict__ cursor, int n) {
  __shared__ int lds[256];
  int t = threadIdx.x, base = blockIdx.x * 2048 + t * 8;
  int c[8]; int s = 0;
#pragma unroll
  for (int j = 0; j < 8; ++j) { int i = base + j; c[j] = (i < n) ? cnt[i] : 0; s += c[j]; }
  lds[t] = s; __syncthreads();
  for (int off = 1; off < 256; off <<= 1) {
    int x = lds[t];
    int a = (t >= off) ? lds[t - off] : 0;
    __syncthreads();
    lds[t] = x + a;
    __syncthreads();
  }
  int run = partial[blockIdx.x] + lds[t] - s;  // exclusive prefix for this thread
#pragma unroll
  for (int j = 0; j < 8; ++j) {
    int i = base + j;
    if (i < n) { row_ptr[i] = run; cursor[i] = run; }
    run += c[j];
  }
}

__global__ __launch_bounds__(256) void bucket_kernel(
    const int* __restrict__ src1, const int* __restrict__ dst1,
    const int* __restrict__ src2, const int* __restrict__ dst2,
    int* __restrict__ cursor, int* __restrict__ nbr, int E, int N) {
  int e = blockIdx.x * blockDim.x + threadIdx.x;
  int key, val;
  if (e < E)          { key = src1[e];         val = dst1[e]; }
  else if (e < 2 * E) { key = N + src2[e - E]; val = dst2[e - E]; }
  else return;
  int pos = atomicAdd(&cursor[key], 1);
  nbr[pos] = val;
}

// ---------------------------------------------------------------------------
// Gather-mean: one wave per key v in [0,2N). Lane j owns column j; each
// neighbor row is a 256B coalesced read from g (g1+g2 = 23MB, L2/L3-resident).
// avg = sum/deg (deg==0 -> 0), written dense -> finalize needs no counts.
// ---------------------------------------------------------------------------
__global__ __launch_bounds__(256) void aggregate_kernel(
    const int* __restrict__ row_ptr, const int* __restrict__ nbr,
    const float* __restrict__ g1, const float* __restrict__ g2,
    float* __restrict__ avg1, float* __restrict__ avg2, int N) {
  int lane = threadIdx.x & 63;
  int v = blockIdx.x * 4 + (threadIdx.x >> 6);
  if (v >= 2 * N) return;
  int n0 = row_ptr[v], n1 = row_ptr[v + 1];
  const float* __restrict__ g = (v < N) ? g1 : g2;
  float acc = 0.f;
  for (int base = n0; base < n1; base += 64) {
    int rem = n1 - base;
    int m = rem < 64 ? rem : 64;
    int idx = (lane < m) ? nbr[base + lane] : 0;
    int j = 0;
    for (; j + 4 <= m; j += 4) {  // 4 independent gathers in flight
      int d0 = __shfl(idx, j), d1 = __shfl(idx, j + 1);
      int d2 = __shfl(idx, j + 2), d3 = __shfl(idx, j + 3);
      float v0 = g[(size_t)d0 * 64 + lane];
      float v1 = g[(size_t)d1 * 64 + lane];
      float v2 = g[(size_t)d2 * 64 + lane];
      float v3 = g[(size_t)d3 * 64 + lane];
      acc += v0 + v1 + v2 + v3;
    }
    for (; j < m; ++j) {
      int d = __shfl(idx, j);
      acc += g[(size_t)d * 64 + lane];
    }
  }
  int deg = n1 - n0;
  float a = (deg > 0) ? acc / (float)deg : 0.f;
  if (v < N) avg1[(size_t)v * 64 + lane] = a;
  else       avg2[(size_t)(v - N) * 64 + lane] = a;
}

// ---------------------------------------------------------------------------
// Finalize: one thread per float4. t from out plane 4, m staged in plane 1.
// ---------------------------------------------------------------------------
__global__ __launch_bounds__(256) void finalize_kernel(
    const float* __restrict__ avg1, const float* __restrict__ avg2,
    float* __restrict__ out, int N) {
  int i = blockIdx.x * blockDim.x + threadIdx.x;
  if (i >= N * 16) return;
  size_t base  = ((size_t)i) << 2;
  size_t plane = (size_t)N * 64;
  f32x4 t = *(const f32x4*)(out + 4 * plane + base);
  f32x4 m = *(const f32x4*)(out + plane + base);
  f32x4 a1 = *(const f32x4*)(avg1 + base);
  f32x4 a2 = *(const f32x4*)(avg2 + base);
  f32x4 v1, m1, v2, m2;
#pragma unroll
  for (int j = 0; j < 4; ++j) {
    v1[j] = eluf(t[j] + a1[j]);
    m1[j] = eluf(m[j] + a1[j]);
    v2[j] = eluf(t[j] + a2[j]);
    m2[j] = eluf(m[j] + a2[j]);
  }
  *(f32x4*)(out + base)             = v1;
  *(f32x4*)(out + plane + base)     = m1;
  *(f32x4*)(out + 2 * plane + base) = v2;
  *(f32x4*)(out + 3 * plane + base) = m2;
}

static inline int imin(int a, int b) { return a < b ? a : b; }

extern "C" void kernel_launch(void* const* d_in, const int* in_sizes, int n_in,
                              void* d_out, int out_size, void* d_ws, size_t ws_size,
                              hipStream_t stream) {
  const float* feats0 = (const float*)d_in[0];
  const float* feats1 = (const float*)d_in[1];
  const float* feats2 = (const float*)d_in[2];
  const float* maskf  = (const float*)d_in[3];
  const int* src1 = (const int*)d_in[4];
  const int* dst1 = (const int*)d_in[5];
  const int* src2 = (const int*)d_in[6];
  const int* dst2 = (const int*)d_in[7];
  const float* W0 = (const float*)d_in[8];
  const float* b0 = (const float*)d_in[9];
  const float* W1 = (const float*)d_in[10];
  const float* b1 = (const float*)d_in[11];
  const float* W2 = (const float*)d_in[12];
  const float* b2 = (const float*)d_in[13];
  const float* A0 = (const float*)d_in[14];
  const float* A1 = (const float*)d_in[15];

  int N  = in_sizes[0] / 128;
  int N1 = in_sizes[1] / 128;
  int N2 = in_sizes[2] / 128;
  int E  = in_sizes[4];
  int M  = 2 * N;                    // CSR key space (both relations)

  float* out = (float*)d_out;
  size_t plane = (size_t)N * 64;
  float* h_tar  = out + 4 * plane;   // final value of plane 4 IS h_tar
  float* h_mask = out + plane;       // staged; finalize overwrites with mask1

  // Workspace (~90 MB; R0 validated ws_size >= ~126 MB)
  float* g1      = (float*)d_ws;               // N1*64
  float* g2      = g1 + (size_t)N1 * 64;       // N2*64
  float* avg1    = g2 + (size_t)N2 * 64;       // N*64
  float* avg2    = avg1 + (size_t)N * 64;      // N*64
  int*   cnt     = (int*)(avg2 + (size_t)N * 64);  // M
  int*   row_ptr = cnt + M;                    // M+1
  int*   cursor  = row_ptr + M + 1;            // M
  int*   partial = cursor + M;                 // <=256
  int*   nbr     = partial + 256;              // 2E
  ushort* frags  = (ushort*)(nbr + 2 * E);     // 32768 ushorts (64 KB)

  hipMemsetAsync(cnt, 0, (size_t)M * sizeof(int), stream);

  pack_frags_kernel<<<16, 256, 0, stream>>>(W0, W1, W2, A0, A1, frags);

  int t0 = N / 16, t1 = N1 / 16, t2 = N2 / 16;
  lin_elu_kernel<false><<<imin(2048, (t0 + 3) / 4), 256, 0, stream>>>(
      feats0, frags, b0, nullptr, h_tar, t0);
  lin_elu_kernel<false><<<imin(2048, (t0 + 3) / 4), 256, 0, stream>>>(
      maskf, frags, b0, nullptr, h_mask, t0);
  lin_elu_kernel<true><<<imin(2048, (t1 + 3) / 4), 256, 0, stream>>>(
      feats1, frags + 8192, b1, frags + 24576, g1, t1);
  lin_elu_kernel<true><<<imin(2048, (t2 + 3) / 4), 256, 0, stream>>>(
      feats2, frags + 16384, b2, frags + 28672, g2, t2);

  // CSR build
  count_kernel<<<(2 * E + 255) / 256, 256, 0, stream>>>(src1, src2, cnt, E, N);
  int nb = (M + 2047) / 2048;  // 98 for N=100000; fits single-block stage 2
  scan_sums_kernel<<<nb, 256, 0, stream>>>(cnt, partial, M);
  scan_partials_kernel<<<1, 256, 0, stream>>>(partial, row_ptr, nb, M);
  scan_write_kernel<<<nb, 256, 0, stream>>>(cnt, partial, row_ptr, cursor, M);
  bucket_kernel<<<(2 * E + 255) / 256, 256, 0, stream>>>(
      src1, dst1, src2, dst2, cursor, nbr, E, N);

  // Gather-mean
  aggregate_kernel<<<(M + 3) / 4, 256, 0, stream>>>(
      row_ptr, nbr, g1, g2, avg1, avg2, N);

  finalize_kernel<<<(N * 16 + 255) / 256, 256, 0, stream>>>(avg1, avg2, out, N);
}